// Round 11
// baseline (359.114 us; speedup 1.0000x reference)
//
#include <hip/hip_runtime.h>
#include <hip/hip_bf16.h>
#include <cstdint>

#define BB 4
#define HH 8
#define LL 2048
#define DD 64
#define SK 40
#define NT 40
#define BHN (BB*HH)            // 32
#define SCALE 0.125f
#define CHUNK 128
#define NCH (LL/CHUNK)         // 16
#define USPL 2
#define UPB (NT/USPL)          // 20 u-rows per k3a block

// k1 chunking
#define KC 8                   // K chunks
#define KCR (LL/KC)            // 256 rows per chunk
#define KPAD 68                // padded LDS row stride (floats), 16B-aligned

// workspace layout in floats
#define WS_M    0                          // (now unused)
#define WS_SUB  (WS_M + BHN*LL)            // [BHN*64*DD]         = 131072
#define WS_CTX  (WS_SUB + BHN*64*DD)       // repurposed: rows8 (80KB) + off8 (16KB)
#define WS_PM   (WS_CTX + BHN*NT*DD)       // [BHN*NT*NCH]        = 20480
#define WS_PSUM (WS_PM + BHN*NT*NCH)       // [BHN*NT*NCH]        = 20480
#define WS_PACC (WS_PSUM + BHN*NT*NCH)     // [BHN*NT*NCH*DD] = 1310720; first 1048576 aliased by pmax8/psum8 (dead before k3a)
#define WS_TOP  (WS_PACC + BHN*NT*NCH*DD)  // int [BHN*NT]

#define K4A_BLOCKS (BHN * 64)      // 2048
#define K4B_BLOCKS (BHN * 64)      // 2048
#define PRE_BLOCKS (LL / 256)      // 8

static __device__ __forceinline__ float4 f4add(float4 a, float4 b) {
    float4 r; r.x = a.x + b.x; r.y = a.y + b.y; r.z = a.z + b.z; r.w = a.w + b.w; return r;
}

// ================= F0: [precompute sample lists || k4a] =================
// blocks [0,8): per-l counting sort of the 40 samples by 256-row chunk.
//   rows8[l][40]: row-within-chunk bytes, grouped by chunk; off8[l]: packed
//   6-bit inclusive ends per chunk. index_sample is shared across bh -> one copy.
// blocks [8, 8+2048): k4a 32-row chunk sums of V.
__global__ __launch_bounds__(256) void f0_pre_sub(const int* __restrict__ isamp,
                                                  const float* __restrict__ V,
                                                  unsigned char* __restrict__ rows8,
                                                  unsigned long long* __restrict__ off8,
                                                  float* __restrict__ sub) {
    int bid = blockIdx.x;
    if (bid < PRE_BLOCKS) {
        int l = bid * 256 + threadIdx.x;
        int idxr[SK];
#pragma unroll
        for (int s = 0; s < SK; s++) idxr[s] = isamp[l * SK + s];
        unsigned long long off = 0ull;
        int end = 0;
#pragma unroll
        for (int c = 0; c < KC; c++) {
            int p = end;                       // start of chunk c
#pragma unroll
            for (int s = 0; s < SK; s++) {
                if ((idxr[s] >> 8) == c) {
                    rows8[l * SK + p] = (unsigned char)(idxr[s] & 255);
                    p++;
                }
            }
            end = p;
            off |= (unsigned long long)end << (6 * c);
        }
        off8[l] = off;
    } else {
        __shared__ float4 part[16][16];
        int blk = bid - PRE_BLOCKS;
        int t = threadIdx.x;
        int d4 = t & 15, rg = t >> 4;
        const float4* v4 = reinterpret_cast<const float4*>(V) + (size_t)blk * 32 * 16 + (size_t)rg * 2 * 16 + d4;
        float4 a = v4[0], b = v4[16];
        part[rg][d4] = f4add(a, b);
        __syncthreads();
#pragma unroll
        for (int step = 8; step; step >>= 1) {
            if (rg < step) part[rg][d4] = f4add(part[rg][d4], part[rg + step][d4]);
            __syncthreads();
        }
        if (rg == 0)
            reinterpret_cast<float4*>(sub)[(size_t)blk * 16 + d4] = part[0][d4];
    }
}

// ================= K1: chunked-LDS sampled scoring =================
// block = (bh, chunk c, l-half). Stage K rows [c*256,(c+1)*256) into LDS once
// (each row then gathered ~40x from LDS instead of L2). 16-lane groups, one l
// per group, walk the precomputed in-chunk list. Emits per-chunk partial
// (max, sum); merged in F2's k2 path. Block->XCD mapping keeps the l-half
// pair + 4 bh on one XCD (K/Q panels L2-resident).
__global__ __launch_bounds__(256) void k1_chunk(const float* __restrict__ Q,
                                                const float* __restrict__ K,
                                                const unsigned char* __restrict__ rows8,
                                                const unsigned long long* __restrict__ off8,
                                                float* __restrict__ pmax8,
                                                float* __restrict__ psum8) {
    extern __shared__ float K_lds[];          // [KCR][KPAD] = 69632 B
    int bid = blockIdx.x;
    int x = bid & 7;                // XCD (dispatch round-robin)
    int kslot = bid >> 3;           // 0..63
    int g = x * 32 + (kslot & 31);  // (bh,c) id: 4 bh per XCD
    int lhalf = kslot >> 5;
    int bh = g >> 3, c = g & 7;
    int tid = threadIdx.x;

    // stage K chunk: 256 rows x 16 float4, padded stride
    const float4* Ksrc = reinterpret_cast<const float4*>(K + ((size_t)bh * LL + c * KCR) * DD);
#pragma unroll
    for (int i = tid; i < KCR * 16; i += 256) {
        int row = i >> 4, e = i & 15;
        *reinterpret_cast<float4*>(&K_lds[row * KPAD + e * 4]) = Ksrc[i];
    }
    __syncthreads();

    int w = tid >> 6, lane = tid & 63;
    int g4 = lane >> 4, e = lane & 15;
    for (int iter = 0; iter < 64; iter++) {
        int l = lhalf * 1024 + iter * 16 + w * 4 + g4;
        unsigned long long off = off8[l];
        int start = c ? (int)((off >> (6 * (c - 1))) & 63) : 0;
        int end   = (int)((off >> (6 * c)) & 63);
        float4 q = *reinterpret_cast<const float4*>(Q + ((size_t)bh * LL + l) * DD + e * 4);
        float mx = -INFINITY, sm = 0.f;
        for (int j = start; j < end; j++) {
            int r = rows8[l * SK + j];                       // broadcast byte
            float4 kv = *reinterpret_cast<const float4*>(&K_lds[r * KPAD + e * 4]);
            float d = q.x * kv.x + q.y * kv.y + q.z * kv.z + q.w * kv.w;
            d += __shfl_xor(d, 1);
            d += __shfl_xor(d, 2);
            d += __shfl_xor(d, 4);
            d += __shfl_xor(d, 8);
            mx = fmaxf(mx, d);
            sm += d;
        }
        if (e == 0) {
            size_t o = ((size_t)c * BHN + bh) * LL + l;
            pmax8[o] = mx;                                   // -inf if empty
            psum8[o] = sm;
        }
    }
}

// ================= F2: [k2(merge+top-40) || k4b_scan] =================
__global__ __launch_bounds__(256) void f2_topk_scan(const float* __restrict__ pmax8,
                                                    const float* __restrict__ psum8,
                                                    int* __restrict__ Mtop,
                                                    const float* __restrict__ V,
                                                    const float* __restrict__ sub,
                                                    float* __restrict__ out) {
    int bid = blockIdx.x;
    if (bid < BHN) {
        // ---- k2: merge chunk partials into M on the fly, then top-40 ----
        int lane = threadIdx.x;
        if (lane >= 64) return;
        int bh = bid;
        unsigned long long key[32];
#pragma unroll
        for (int j = 0; j < 32; j++) {
            int i = lane + j * 64;
            float mx = -INFINITY, sm = 0.f;
#pragma unroll
            for (int c = 0; c < KC; c++) {
                size_t o = ((size_t)c * BHN + bh) * LL + i;
                mx = fmaxf(mx, pmax8[o]);
                sm += psum8[o];
            }
            float v = mx - sm * (1.0f / (float)LL);
            unsigned u = __float_as_uint(v);
            u = (u & 0x80000000u) ? ~u : (u | 0x80000000u);
            key[j] = ((unsigned long long)u << 32) | (unsigned)(~i);
        }
        unsigned long long winner = 0ull;
        for (int t = 0; t < NT; t++) {
            unsigned long long best = 0ull;
#pragma unroll
            for (int j = 0; j < 32; j++) {
                unsigned long long k = key[j];
                k = (k == winner) ? 0ull : k;
                key[j] = k;
                best = (k > best) ? k : best;
            }
#pragma unroll
            for (int off = 32; off; off >>= 1) {
                unsigned long long o = __shfl_xor(best, off);
                best = (o > best) ? o : best;
            }
            winner = best;
            if (lane == 0) Mtop[bh * NT + t] = (int)(~(unsigned)(best & 0xFFFFFFFFull));
        }
    } else {
        // ---- k4b: inclusive cumsum of V into out ----
        __shared__ float4 plds[16][16];
        int blk = bid - BHN;
        int bh = blk >> 6, j = blk & 63;
        int t = threadIdx.x;
        int d4 = t & 15, rg = t >> 4;

        const float4* sub4 = reinterpret_cast<const float4*>(sub) + (size_t)(bh * 64) * 16 + d4;
        float4 off = {0.f, 0.f, 0.f, 0.f};
        for (int p = 0; p < j; p++) off = f4add(off, sub4[(size_t)p * 16]);

        const float4* v4 = reinterpret_cast<const float4*>(V) + (size_t)blk * 32 * 16 + (size_t)rg * 2 * 16 + d4;
        float4 a = v4[0], b = v4[16];
        plds[rg][d4] = f4add(a, b);
        __syncthreads();
        float4 ex = {0.f, 0.f, 0.f, 0.f};
        for (int p = 0; p < rg; p++) ex = f4add(ex, plds[p][d4]);

        float4 r0 = f4add(f4add(off, ex), a);
        float4 r1 = f4add(r0, b);
        float4* o4 = reinterpret_cast<float4*>(out) + (size_t)blk * 32 * 16 + (size_t)rg * 2 * 16 + d4;
        o4[0] = r0;
        o4[16] = r1;
    }
}

// ================= K3a: chunked partial attention (USPL=2, vectorized PV) =================
__global__ __launch_bounds__(256) void k3a_partial(const float* __restrict__ Q,
                                                   const float* __restrict__ K,
                                                   const float* __restrict__ V,
                                                   const int* __restrict__ Mtop,
                                                   float* __restrict__ pm,
                                                   float* __restrict__ psum,
                                                   float* __restrict__ pacc) {
    __shared__ float q_lds[UPB * DD];      // 5 KB
    __shared__ float s_lds[UPB][CHUNK];    // 10 KB
    __shared__ int   qi_lds[UPB];
    int bid = blockIdx.x;
    int swz = (bid & 7) * (BHN * NCH * USPL / 8) + (bid >> 3);   // 1024%8==0
    int bh  = swz >> 5;
    int rem = swz & 31;
    int ch  = rem >> 1;
    int u0  = (rem & 1) * UPB;
    int ck  = ch * CHUNK;
    int tid = threadIdx.x;

    if (tid < UPB) qi_lds[tid] = Mtop[bh * NT + u0 + tid];
    __syncthreads();
    for (int c = tid; c < UPB * 16; c += 256) {
        int u = c >> 4, j = c & 15;
        reinterpret_cast<float4*>(q_lds)[c] =
            reinterpret_cast<const float4*>(Q + ((size_t)bh * LL + qi_lds[u]) * DD)[j];
    }
    __syncthreads();

    // scores: thread pair (half 0/1) per key; K half-row in registers
    int k    = ck + (tid >> 1);
    int half = tid & 1;
    const float4* krow = reinterpret_cast<const float4*>(K + ((size_t)bh * LL + k) * DD) + half * 8;
    float4 kreg[8];
#pragma unroll
    for (int j = 0; j < 8; j++) kreg[j] = krow[j];
#pragma unroll 4
    for (int u = 0; u < UPB; u++) {
        const float4* q4 = reinterpret_cast<const float4*>(q_lds + u * DD) + half * 8;
        float d = 0.f;
#pragma unroll
        for (int j = 0; j < 8; j++) {
            float4 a = q4[j], b = kreg[j];
            d += a.x * b.x + a.y * b.y + a.z * b.z + a.w * b.w;
        }
        d += __shfl_xor(d, 1);
        float s = (k <= qi_lds[u]) ? d * SCALE : -INFINITY;
        if (half == 0) s_lds[u][k - ck] = s;
    }
    __syncthreads();

    // per-u local max + expsum; wave w owns u = w + 4*uu (uu < 5)
    int w = tid >> 6, lane = tid & 63;
#pragma unroll
    for (int uu = 0; uu < UPB / 4; uu++) {
        int u = w + uu * 4;
        float s0 = s_lds[u][lane], s1 = s_lds[u][lane + 64];
        float m = fmaxf(s0, s1);
#pragma unroll
        for (int off = 32; off; off >>= 1) m = fmaxf(m, __shfl_xor(m, off));
        float e0 = (s0 == -INFINITY) ? 0.f : __expf(s0 - m);
        float e1 = (s1 == -INFINITY) ? 0.f : __expf(s1 - m);
        s_lds[u][lane] = e0;
        s_lds[u][lane + 64] = e1;
        float smv = e0 + e1;
#pragma unroll
        for (int off = 32; off; off >>= 1) smv += __shfl_xor(smv, off);
        if (lane == 0) {
            size_t rg = (size_t)bh * NT + u0 + u;
            pm  [rg * NCH + ch] = m;
            psum[rg * NCH + ch] = smv;
        }
    }
    __syncthreads();

    // partial PV, vectorized: lane = (d4 = lane&15, kp = lane>>4)
    int d4 = lane & 15, kp = lane >> 4;
    float4 acc[UPB / 4];
#pragma unroll
    for (int uu = 0; uu < UPB / 4; uu++) acc[uu] = make_float4(0.f, 0.f, 0.f, 0.f);
    const float4* v4 = reinterpret_cast<const float4*>(V + ((size_t)bh * LL + ck) * DD) + d4;
#pragma unroll 4
    for (int kb = 0; kb < CHUNK; kb += 4) {
        int kk = kb + kp;
        float4 v = v4[(size_t)kk * 16];
#pragma unroll
        for (int uu = 0; uu < UPB / 4; uu++) {
            float s = s_lds[w + uu * 4][kk];
            acc[uu].x += s * v.x;
            acc[uu].y += s * v.y;
            acc[uu].z += s * v.z;
            acc[uu].w += s * v.w;
        }
    }
#pragma unroll
    for (int uu = 0; uu < UPB / 4; uu++) {
        float4 a = acc[uu];
        a.x += __shfl_xor(a.x, 16); a.x += __shfl_xor(a.x, 32);
        a.y += __shfl_xor(a.y, 16); a.y += __shfl_xor(a.y, 32);
        a.z += __shfl_xor(a.z, 16); a.z += __shfl_xor(a.z, 32);
        a.w += __shfl_xor(a.w, 16); a.w += __shfl_xor(a.w, 32);
        if (kp == 0) {
            size_t rg = (size_t)bh * NT + u0 + w + uu * 4;
            reinterpret_cast<float4*>(pacc + (rg * NCH + ch) * DD)[d4] = a;
        }
    }
}

// ================= K3b: merge chunk partials, scatter to out (after F2) =================
__global__ __launch_bounds__(64) void k3b_scatter(const float* __restrict__ pm,
                                                  const float* __restrict__ psum,
                                                  const float* __restrict__ pacc,
                                                  const int* __restrict__ Mtop,
                                                  float* __restrict__ out) {
    int row = blockIdx.x;            // bh*NT + u
    int lane = threadIdx.x;          // = d
    int bh = row / NT;
    float pmv[NCH];
    float m = -INFINITY;
#pragma unroll
    for (int i = 0; i < NCH; i++) {
        pmv[i] = pm[(size_t)row * NCH + i];
        m = fmaxf(m, pmv[i]);
    }
    float Z = 0.f, acc = 0.f;
#pragma unroll
    for (int i = 0; i < NCH; i++) {
        float sc = (pmv[i] == -INFINITY) ? 0.f : __expf(pmv[i] - m);
        Z   += psum[(size_t)row * NCH + i] * sc;
        acc += pacc[((size_t)row * NCH + i) * DD + lane] * sc;
    }
    int qi = Mtop[row];
    out[((size_t)bh * LL + qi) * DD + lane] = acc / Z;
}

extern "C" void kernel_launch(void* const* d_in, const int* in_sizes, int n_in,
                              void* d_out, int out_size, void* d_ws, size_t ws_size,
                              hipStream_t stream) {
    const float* Q = (const float*)d_in[0];
    const float* K = (const float*)d_in[1];
    const float* V = (const float*)d_in[2];
    const int* isamp = (const int*)d_in[3];
    float* ws   = (float*)d_ws;
    float* sub  = ws + WS_SUB;
    float* pm   = ws + WS_PM;
    float* psum = ws + WS_PSUM;
    float* pacc = ws + WS_PACC;
    int*   Mtop = (int*)(ws + WS_TOP);
    float* out  = (float*)d_out;

    // sample lists in the (free) CTX region; chunk partials alias pacc
    // (pacc is written only later, by k3a).
    unsigned char* rows8 = (unsigned char*)(ws + WS_CTX);                  // 80 KB
    unsigned long long* off8 = (unsigned long long*)(ws + WS_CTX + 20480); // 16 KB
    float* pmax8 = pacc;                    // [KC][BHN][LL] = 524288
    float* psum8 = pacc + (size_t)KC * BHN * LL;

    f0_pre_sub <<<PRE_BLOCKS + K4A_BLOCKS, 256, 0, stream>>>(isamp, V, rows8, off8, sub);
    k1_chunk   <<<BHN * KC * 2, 256, KCR * KPAD * 4, stream>>>(Q, K, rows8, off8, pmax8, psum8);
    f2_topk_scan<<<BHN + K4B_BLOCKS, 256, 0, stream>>>(pmax8, psum8, Mtop, V, sub, out);
    k3a_partial<<<BHN * NCH * USPL, 256, 0, stream>>>(Q, K, V, Mtop, pm, psum, pacc);
    k3b_scatter<<<BHN * NT, 64, 0, stream>>>(pm, psum, pacc, Mtop, out);
}

// Round 13
// 203.522 us; speedup vs baseline: 1.7645x; 1.7645x over previous
//
#include <hip/hip_runtime.h>
#include <hip/hip_bf16.h>
#include <cstdint>

#define BB 4
#define HH 8
#define LL 2048
#define DD 64
#define SK 40
#define NT 40
#define BHN (BB*HH)            // 32
#define SCALE 0.125f
#define CHUNK 128
#define NCH (LL/CHUNK)         // 16
#define USPL 2
#define UPB (NT/USPL)          // 20 u-rows per k3a block

// workspace layout in floats
#define WS_M    0                          // [BHN*LL]            = 65536
#define WS_SUB  (WS_M + BHN*LL)            // [BHN*64*DD]         = 131072
#define WS_CTX  (WS_SUB + BHN*64*DD)       // (unused)
#define WS_PM   (WS_CTX + BHN*NT*DD)       // [BHN*NT*NCH]        = 20480
#define WS_PSUM (WS_PM + BHN*NT*NCH)       // [BHN*NT*NCH]        = 20480
#define WS_PACC (WS_PSUM + BHN*NT*NCH)     // [BHN*NT*NCH*DD]     = 1310720
#define WS_TOP  (WS_PACC + BHN*NT*NCH*DD)  // int [BHN*NT]

#define K1_BLOCKS (BHN * LL / 4)   // 16384
#define K4A_BLOCKS (BHN * 64)      // 2048
#define K4B_BLOCKS (BHN * 64)      // 2048

static __device__ __forceinline__ float4 f4add(float4 a, float4 b) {
    float4 r; r.x = a.x + b.x; r.y = a.y + b.y; r.z = a.z + b.z; r.w = a.w + b.w; return r;
}

static __device__ __forceinline__ float f4dot(float4 a, float4 b) {
    return a.x * b.x + a.y * b.y + a.z * b.z + a.w * b.w;
}

// ================= F1: [k1 || k4a] =================
// k1 mapping: one wave per (bh,l); lane = (s_local = lane>>2, quarter =
// lane&3). Each lane dots a 16-float quarter of sampled row s = pass*16 +
// s_local against the matching Q quarter (4 independent float4 gathers ->
// real MLP), then 2 shfls reduce over quarters. 3 passes cover 40 samples.
// 18 shfl insts/wave vs 44 in the old 16-lane-group scheme, chain depth 2 vs 4.
__global__ __launch_bounds__(256) void f1_m_sub(const float* __restrict__ Q,
                                                const float* __restrict__ K,
                                                const int* __restrict__ isamp,
                                                const float* __restrict__ V,
                                                float* __restrict__ M,
                                                float* __restrict__ sub) {
    int bid = blockIdx.x;
    if (bid < K1_BLOCKS) {
        int swz  = (bid & 7) * (K1_BLOCKS / 8) + (bid >> 3);   // bijective XCD swizzle
        int wid  = swz * 4 + (threadIdx.x >> 6);   // = bh*LL + l
        int lane = threadIdx.x & 63;
        int bh   = wid >> 11;
        int l    = wid & (LL - 1);
        int quarter = lane & 3;
        int sl      = lane >> 2;       // 0..15

        const float4* qb = reinterpret_cast<const float4*>(Q + (size_t)wid * DD) + quarter * 4;
        float4 q0 = qb[0], q1 = qb[1], q2 = qb[2], q3 = qb[3];

        const float* Kbh = K + (size_t)bh * LL * DD;
        const int* irow = isamp + l * SK;
        int idxs[3];
        idxs[0] = irow[sl];
        idxs[1] = irow[16 + sl];
        idxs[2] = (sl < 8) ? irow[32 + sl] : irow[39];

        float mx = -INFINITY, sm = 0.f;
#pragma unroll
        for (int p = 0; p < 3; p++) {
            bool act = (p < 2) | (sl < 8);
            const float4* kb = reinterpret_cast<const float4*>(Kbh + (size_t)idxs[p] * DD) + quarter * 4;
            float4 k0 = kb[0], k1v = kb[1], k2v = kb[2], k3v = kb[3];
            float d = f4dot(q0, k0) + f4dot(q1, k1v) + f4dot(q2, k2v) + f4dot(q3, k3v);
            d += __shfl_xor(d, 1);
            d += __shfl_xor(d, 2);               // quarter==0 now holds full dot
            float dv = (act && quarter == 0) ? d : -INFINITY;
            float ds = (act && quarter == 0) ? d : 0.f;
            mx = fmaxf(mx, dv);
            sm += ds;
        }
#pragma unroll
        for (int off = 32; off; off >>= 1) {
            mx = fmaxf(mx, __shfl_xor(mx, off));
            sm += __shfl_xor(sm, off);
        }
        if (lane == 0) M[wid] = mx - sm * (1.0f / (float)LL);
    } else {
        // ---- k4a body ----
        __shared__ float4 part[16][16];
        int blk = bid - K1_BLOCKS;
        int t = threadIdx.x;
        int d4 = t & 15, rg = t >> 4;
        const float4* v4 = reinterpret_cast<const float4*>(V) + (size_t)blk * 32 * 16 + (size_t)rg * 2 * 16 + d4;
        float4 a = v4[0], b = v4[16];
        part[rg][d4] = f4add(a, b);
        __syncthreads();
#pragma unroll
        for (int step = 8; step; step >>= 1) {
            if (rg < step) part[rg][d4] = f4add(part[rg][d4], part[rg + step][d4]);
            __syncthreads();
        }
        if (rg == 0)
            reinterpret_cast<float4*>(sub)[(size_t)blk * 16 + d4] = part[0][d4];
    }
}

// ================= F2: [k2 || k4b_scan] =================
__global__ __launch_bounds__(256) void f2_topk_scan(const float* __restrict__ M,
                                                    int* __restrict__ Mtop,
                                                    const float* __restrict__ V,
                                                    const float* __restrict__ sub,
                                                    float* __restrict__ out) {
    int bid = blockIdx.x;
    if (bid < BHN) {
        // ---- k2: register-resident top-40, one wave, no barriers ----
        int lane = threadIdx.x;
        if (lane >= 64) return;
        int bh = bid;
        const float* Mb = M + (size_t)bh * LL;
        unsigned long long key[32];
#pragma unroll
        for (int j = 0; j < 32; j++) {
            int i = lane + j * 64;
            unsigned u = __float_as_uint(Mb[i]);
            u = (u & 0x80000000u) ? ~u : (u | 0x80000000u);
            key[j] = ((unsigned long long)u << 32) | (unsigned)(~i);
        }
        unsigned long long winner = 0ull;
        for (int t = 0; t < NT; t++) {
            unsigned long long best = 0ull;
#pragma unroll
            for (int j = 0; j < 32; j++) {
                unsigned long long k = key[j];
                k = (k == winner) ? 0ull : k;
                key[j] = k;
                best = (k > best) ? k : best;
            }
#pragma unroll
            for (int off = 32; off; off >>= 1) {
                unsigned long long o = __shfl_xor(best, off);
                best = (o > best) ? o : best;
            }
            winner = best;
            if (lane == 0) Mtop[bh * NT + t] = (int)(~(unsigned)(best & 0xFFFFFFFFull));
        }
    } else {
        // ---- k4b: inclusive cumsum of V into out ----
        __shared__ float4 plds[16][16];
        int blk = bid - BHN;
        int bh = blk >> 6, j = blk & 63;
        int t = threadIdx.x;
        int d4 = t & 15, rg = t >> 4;

        const float4* sub4 = reinterpret_cast<const float4*>(sub) + (size_t)(bh * 64) * 16 + d4;
        float4 off = {0.f, 0.f, 0.f, 0.f};
        for (int p = 0; p < j; p++) off = f4add(off, sub4[(size_t)p * 16]);

        const float4* v4 = reinterpret_cast<const float4*>(V) + (size_t)blk * 32 * 16 + (size_t)rg * 2 * 16 + d4;
        float4 a = v4[0], b = v4[16];
        plds[rg][d4] = f4add(a, b);
        __syncthreads();
        float4 ex = {0.f, 0.f, 0.f, 0.f};
        for (int p = 0; p < rg; p++) ex = f4add(ex, plds[p][d4]);

        float4 r0 = f4add(f4add(off, ex), a);
        float4 r1 = f4add(r0, b);
        float4* o4 = reinterpret_cast<float4*>(out) + (size_t)blk * 32 * 16 + (size_t)rg * 2 * 16 + d4;
        o4[0] = r0;
        o4[16] = r1;
    }
}

// ================= K3a: chunked partial attention (USPL=2, vectorized PV) =================
__global__ __launch_bounds__(256) void k3a_partial(const float* __restrict__ Q,
                                                   const float* __restrict__ K,
                                                   const float* __restrict__ V,
                                                   const int* __restrict__ Mtop,
                                                   float* __restrict__ pm,
                                                   float* __restrict__ psum,
                                                   float* __restrict__ pacc) {
    __shared__ float q_lds[UPB * DD];      // 5 KB
    __shared__ float s_lds[UPB][CHUNK];    // 10 KB
    __shared__ int   qi_lds[UPB];
    int bid = blockIdx.x;
    int swz = (bid & 7) * (BHN * NCH * USPL / 8) + (bid >> 3);   // 1024%8==0
    int bh  = swz >> 5;
    int rem = swz & 31;
    int ch  = rem >> 1;
    int u0  = (rem & 1) * UPB;
    int ck  = ch * CHUNK;
    int tid = threadIdx.x;

    if (tid < UPB) qi_lds[tid] = Mtop[bh * NT + u0 + tid];
    __syncthreads();
    for (int c = tid; c < UPB * 16; c += 256) {
        int u = c >> 4, j = c & 15;
        reinterpret_cast<float4*>(q_lds)[c] =
            reinterpret_cast<const float4*>(Q + ((size_t)bh * LL + qi_lds[u]) * DD)[j];
    }
    __syncthreads();

    // scores: thread pair (half 0/1) per key; K half-row in registers
    int k    = ck + (tid >> 1);
    int half = tid & 1;
    const float4* krow = reinterpret_cast<const float4*>(K + ((size_t)bh * LL + k) * DD) + half * 8;
    float4 kreg[8];
#pragma unroll
    for (int j = 0; j < 8; j++) kreg[j] = krow[j];
#pragma unroll 4
    for (int u = 0; u < UPB; u++) {
        const float4* q4 = reinterpret_cast<const float4*>(q_lds + u * DD) + half * 8;
        float d = 0.f;
#pragma unroll
        for (int j = 0; j < 8; j++) {
            float4 a = q4[j], b = kreg[j];
            d += a.x * b.x + a.y * b.y + a.z * b.z + a.w * b.w;
        }
        d += __shfl_xor(d, 1);
        float s = (k <= qi_lds[u]) ? d * SCALE : -INFINITY;
        if (half == 0) s_lds[u][k - ck] = s;
    }
    __syncthreads();

    // per-u local max + expsum; wave w owns u = w + 4*uu (uu < 5)
    int w = tid >> 6, lane = tid & 63;
#pragma unroll
    for (int uu = 0; uu < UPB / 4; uu++) {
        int u = w + uu * 4;
        float s0 = s_lds[u][lane], s1 = s_lds[u][lane + 64];
        float m = fmaxf(s0, s1);
#pragma unroll
        for (int off = 32; off; off >>= 1) m = fmaxf(m, __shfl_xor(m, off));
        float e0 = (s0 == -INFINITY) ? 0.f : __expf(s0 - m);
        float e1 = (s1 == -INFINITY) ? 0.f : __expf(s1 - m);
        s_lds[u][lane] = e0;
        s_lds[u][lane + 64] = e1;
        float smv = e0 + e1;
#pragma unroll
        for (int off = 32; off; off >>= 1) smv += __shfl_xor(smv, off);
        if (lane == 0) {
            size_t rg = (size_t)bh * NT + u0 + u;
            pm  [rg * NCH + ch] = m;
            psum[rg * NCH + ch] = smv;
        }
    }
    __syncthreads();

    // partial PV, vectorized: lane = (d4 = lane&15, kp = lane>>4)
    int d4 = lane & 15, kp = lane >> 4;
    float4 acc[UPB / 4];
#pragma unroll
    for (int uu = 0; uu < UPB / 4; uu++) acc[uu] = make_float4(0.f, 0.f, 0.f, 0.f);
    const float4* v4 = reinterpret_cast<const float4*>(V + ((size_t)bh * LL + ck) * DD) + d4;
#pragma unroll 4
    for (int kb = 0; kb < CHUNK; kb += 4) {
        int kk = kb + kp;
        float4 v = v4[(size_t)kk * 16];
#pragma unroll
        for (int uu = 0; uu < UPB / 4; uu++) {
            float s = s_lds[w + uu * 4][kk];
            acc[uu].x += s * v.x;
            acc[uu].y += s * v.y;
            acc[uu].z += s * v.z;
            acc[uu].w += s * v.w;
        }
    }
#pragma unroll
    for (int uu = 0; uu < UPB / 4; uu++) {
        float4 a = acc[uu];
        a.x += __shfl_xor(a.x, 16); a.x += __shfl_xor(a.x, 32);
        a.y += __shfl_xor(a.y, 16); a.y += __shfl_xor(a.y, 32);
        a.z += __shfl_xor(a.z, 16); a.z += __shfl_xor(a.z, 32);
        a.w += __shfl_xor(a.w, 16); a.w += __shfl_xor(a.w, 32);
        if (kp == 0) {
            size_t rg = (size_t)bh * NT + u0 + w + uu * 4;
            reinterpret_cast<float4*>(pacc + (rg * NCH + ch) * DD)[d4] = a;
        }
    }
}

// ================= K3b: merge chunk partials, scatter to out (after F2) =================
__global__ __launch_bounds__(64) void k3b_scatter(const float* __restrict__ pm,
                                                  const float* __restrict__ psum,
                                                  const float* __restrict__ pacc,
                                                  const int* __restrict__ Mtop,
                                                  float* __restrict__ out) {
    int row = blockIdx.x;            // bh*NT + u
    int lane = threadIdx.x;          // = d
    int bh = row / NT;
    float pmv[NCH];
    float m = -INFINITY;
#pragma unroll
    for (int i = 0; i < NCH; i++) {
        pmv[i] = pm[(size_t)row * NCH + i];
        m = fmaxf(m, pmv[i]);
    }
    float Z = 0.f, acc = 0.f;
#pragma unroll
    for (int i = 0; i < NCH; i++) {
        float sc = (pmv[i] == -INFINITY) ? 0.f : __expf(pmv[i] - m);
        Z   += psum[(size_t)row * NCH + i] * sc;
        acc += pacc[((size_t)row * NCH + i) * DD + lane] * sc;
    }
    int qi = Mtop[row];
    out[((size_t)bh * LL + qi) * DD + lane] = acc / Z;
}

extern "C" void kernel_launch(void* const* d_in, const int* in_sizes, int n_in,
                              void* d_out, int out_size, void* d_ws, size_t ws_size,
                              hipStream_t stream) {
    const float* Q = (const float*)d_in[0];
    const float* K = (const float*)d_in[1];
    const float* V = (const float*)d_in[2];
    const int* isamp = (const int*)d_in[3];
    float* ws   = (float*)d_ws;
    float* M    = ws + WS_M;
    float* sub  = ws + WS_SUB;
    float* pm   = ws + WS_PM;
    float* psum = ws + WS_PSUM;
    float* pacc = ws + WS_PACC;
    int*   Mtop = (int*)(ws + WS_TOP);
    float* out  = (float*)d_out;

    f1_m_sub    <<<K1_BLOCKS + K4A_BLOCKS, 256, 0, stream>>>(Q, K, isamp, V, M, sub);
    f2_topk_scan<<<BHN + K4B_BLOCKS,       256, 0, stream>>>(M, Mtop, V, sub, out);
    k3a_partial <<<BHN * NCH * USPL,       256, 0, stream>>>(Q, K, V, Mtop, pm, psum, pacc);
    k3b_scatter <<<BHN * NT,                64, 0, stream>>>(pm, psum, pacc, Mtop, out);
}